// Round 4
// baseline (3399.046 us; speedup 1.0000x reference)
//
#include <hip/hip_runtime.h>

// Problem constants
#define NB 16
#define NH 64
#define NW 64
#define ND 128
#define NK 4096
#define NROWS (NB * NH * NW)        // 65536
#define NSLICE 4
#define SLICE_K (NK / NSLICE)       // 1024
#define KTILE 64
#define OUT_ELEMS (NB * ND * NH * NW)  // 8388608

// ---------------------------------------------------------------------------
// Kernel 1: enorm[k] = ||emb[k]||^2   (one wave per code)
// ---------------------------------------------------------------------------
__global__ void enorm_kernel(const float* __restrict__ emb,
                             float* __restrict__ enorm) {
    int wave = (blockIdx.x * blockDim.x + threadIdx.x) >> 6;
    int lane = threadIdx.x & 63;
    if (wave >= NK) return;
    const float* e = emb + (size_t)wave * ND;
    float a = e[lane];
    float b = e[lane + 64];
    float s = a * a + b * b;
#pragma unroll
    for (int off = 32; off > 0; off >>= 1) s += __shfl_down(s, off, 64);
    if (lane == 0) enorm[wave] = s;
}

// ---------------------------------------------------------------------------
// Kernel 2: argmin, acc-tile form.
// R1-R3 lesson: the compiler reloads any LOADED value (global or LDS) inside
// the k-loop to shrink VGPR use (R3: VGPR=80, L1-bound at ~1050 cyc/k). Only
// COMPUTED values (accumulators) are guaranteed register-resident. So: block
// k into tiles of 64, hold acc[64] per lane (compile-time indices via full
// unroll of kk), and re-read z in 16-float chunks reused across 64 codes
// (z L1 traffic /64). emb/enorm addresses are wave-uniform -> s_load.
// score_k = ||e_k||^2 - 2 z.e_k  (||z||^2 constant per row, dropped)
// ---------------------------------------------------------------------------
__global__ void __launch_bounds__(256, 2)
argmin_kernel(const float* __restrict__ z,
              const float* __restrict__ emb,
              const float* __restrict__ enorm,
              int* __restrict__ idx_out) {
    __shared__ float red_min[NSLICE * 64];
    __shared__ int red_idx[NSLICE * 64];

    const int bid = blockIdx.x;            // 0..1023 row-group
    const int rowbase = bid * 64;
    const int t = threadIdx.x;
    const int lane = t & 63;
    const int wid = __builtin_amdgcn_readfirstlane(t >> 6);  // wave-uniform slice id

    const float* zrow = z + (size_t)(rowbase + lane) * ND;

    float best = 3.4e38f;
    int bidx = 0;
    const int k0 = wid * SLICE_K;

    for (int kt = 0; kt < SLICE_K / KTILE; kt++) {   // 16 tiles of 64 codes
        const int kb = k0 + kt * KTILE;
        float acc[KTILE];
#pragma unroll
        for (int i = 0; i < KTILE; i++) acc[i] = 0.f;

        for (int dc = 0; dc < 8; dc++) {             // 8 chunks of 16 floats
            const float4* z4 = (const float4*)(zrow + dc * 16);
            float4 zc0 = z4[0], zc1 = z4[1], zc2 = z4[2], zc3 = z4[3];
            const float* ebase = emb + (size_t)kb * ND + dc * 16;
#pragma unroll
            for (int kk = 0; kk < KTILE; kk++) {     // FULL unroll: const acc idx
                const float4* e4 = (const float4*)(ebase + (size_t)kk * ND);
                float4 e0 = e4[0], e1 = e4[1], e2 = e4[2], e3 = e4[3];
                float a = acc[kk];
                a = fmaf(zc0.x, e0.x, a); a = fmaf(zc0.y, e0.y, a);
                a = fmaf(zc0.z, e0.z, a); a = fmaf(zc0.w, e0.w, a);
                a = fmaf(zc1.x, e1.x, a); a = fmaf(zc1.y, e1.y, a);
                a = fmaf(zc1.z, e1.z, a); a = fmaf(zc1.w, e1.w, a);
                a = fmaf(zc2.x, e2.x, a); a = fmaf(zc2.y, e2.y, a);
                a = fmaf(zc2.z, e2.z, a); a = fmaf(zc2.w, e2.w, a);
                a = fmaf(zc3.x, e3.x, a); a = fmaf(zc3.y, e3.y, a);
                a = fmaf(zc3.z, e3.z, a); a = fmaf(zc3.w, e3.w, a);
                acc[kk] = a;
            }
        }

#pragma unroll
        for (int kk = 0; kk < KTILE; kk++) {
            float s = fmaf(-2.0f, acc[kk], enorm[kb + kk]);  // uniform s_load
            if (s < best) { best = s; bidx = kb + kk; }      // strict < => first idx
        }
    }

    red_min[wid * 64 + lane] = best;
    red_idx[wid * 64 + lane] = bidx;
    __syncthreads();

    if (wid == 0) {
        float bm = red_min[lane];
        int bi = red_idx[lane];
#pragma unroll
        for (int sl = 1; sl < NSLICE; sl++) {
            float m = red_min[sl * 64 + lane];
            int i2 = red_idx[sl * 64 + lane];
            if (m < bm) { bm = m; bi = i2; }  // ascending slice order => first-idx ties
        }
        idx_out[rowbase + lane] = bi;
    }
}

// ---------------------------------------------------------------------------
// Kernel 3: gather + loss partial + transposed write.
// One block per (b,h): 64 w-positions x 128 d.
// ---------------------------------------------------------------------------
__global__ void out_kernel(const float* __restrict__ z,
                           const float* __restrict__ emb,
                           const int* __restrict__ idx,
                           float* __restrict__ out,
                           float* __restrict__ losspart) {
    __shared__ float zq[64 * 129];
    __shared__ int ids[64];
    __shared__ float redl[4];

    const int bid = blockIdx.x;         // b*64 + h
    const int b = bid >> 6;
    const int h = bid & 63;
    const int rowbase = bid * 64;
    const int t = threadIdx.x;

    if (t < 64) ids[t] = idx[rowbase + t];
    __syncthreads();

    // Pass A: coalesced z reads, emb gather (wave-uniform row), loss accum,
    // fill zq tile in LDS.
    const int d = t & 127;
    const int w0 = t >> 7;
    float lsum = 0.f;
#pragma unroll
    for (int wq = 0; wq < 32; wq++) {
        int w = w0 + 2 * wq;
        float e = emb[(size_t)ids[w] * ND + d];
        float zv = z[((size_t)(rowbase + w)) * ND + d];
        float df = e - zv;
        lsum = fmaf(df, df, lsum);
        zq[w * 129 + d] = e;
    }
#pragma unroll
    for (int off = 32; off > 0; off >>= 1) lsum += __shfl_down(lsum, off, 64);
    if ((t & 63) == 0) redl[t >> 6] = lsum;
    __syncthreads();    // also fences zq writes for pass B
    if (t == 0) losspart[bid] = redl[0] + redl[1] + redl[2] + redl[3];

    // Pass B: out[b][d][h][w], lanes sweep w -> coalesced 256B stores.
    const int w = t & 63;
    const int dq = t >> 6;
#pragma unroll
    for (int dd0 = 0; dd0 < 32; dd0++) {
        int dd = dq + 4 * dd0;
        out[(((size_t)b * ND + dd) * NH + h) * NW + w] = zq[w * 129 + dd];
    }
}

// ---------------------------------------------------------------------------
// Kernel 4: final loss reduce
// ---------------------------------------------------------------------------
__global__ void loss_kernel(const float* __restrict__ losspart,
                            float* __restrict__ out) {
    __shared__ float redl[4];
    const int t = threadIdx.x;
    float s = 0.f;
#pragma unroll
    for (int i = 0; i < 4; i++) s += losspart[t + 256 * i];
#pragma unroll
    for (int off = 32; off > 0; off >>= 1) s += __shfl_down(s, off, 64);
    if ((t & 63) == 0) redl[t >> 6] = s;
    __syncthreads();
    if (t == 0) {
        float total = redl[0] + redl[1] + redl[2] + redl[3];
        out[OUT_ELEMS] = 1.25f * total / (float)OUT_ELEMS;
    }
}

// ---------------------------------------------------------------------------
extern "C" void kernel_launch(void* const* d_in, const int* in_sizes, int n_in,
                              void* d_out, int out_size, void* d_ws, size_t ws_size,
                              hipStream_t stream) {
    const float* z = (const float*)d_in[0];      // [16,64,64,128] fp32
    const float* emb = (const float*)d_in[1];    // [4096,128] fp32
    float* out = (float*)d_out;                  // 8388608 + 1 fp32

    char* ws = (char*)d_ws;
    int* ws_idx = (int*)ws;                          // NROWS ints   (256 KB)
    float* ws_enorm = (float*)(ws + 262144);         // NK floats    (16 KB)
    float* ws_losspart = (float*)(ws + 262144 + 16384);  // 1024 floats

    enorm_kernel<<<NK / 4, 256, 0, stream>>>(emb, ws_enorm);
    argmin_kernel<<<NROWS / 64, 256, 0, stream>>>(z, emb, ws_enorm, ws_idx);
    out_kernel<<<NB * NH, 256, 0, stream>>>(z, emb, ws_idx, out, ws_losspart);
    loss_kernel<<<1, 256, 0, stream>>>(ws_losspart, out);
}

// Round 6
// 1289.188 us; speedup vs baseline: 2.6366x; 2.6366x over previous
//
#include <hip/hip_runtime.h>

// Problem constants
#define NB 16
#define NH 64
#define NW 64
#define ND 128
#define NK 4096
#define NROWS (NB * NH * NW)        // 65536
#define NSLICE 4
#define SLICE_K (NK / NSLICE)       // 1024
#define KTILE 16
#define OUT_ELEMS (NB * ND * NH * NW)  // 8388608

// ---------------------------------------------------------------------------
// Kernel 1: enorm[k] = ||emb[k]||^2   (one wave per code)
// ---------------------------------------------------------------------------
__global__ void enorm_kernel(const float* __restrict__ emb,
                             float* __restrict__ enorm) {
    int wave = (blockIdx.x * blockDim.x + threadIdx.x) >> 6;
    int lane = threadIdx.x & 63;
    if (wave >= NK) return;
    const float* e = emb + (size_t)wave * ND;
    float a = e[lane];
    float b = e[lane + 64];
    float s = a * a + b * b;
#pragma unroll
    for (int off = 32; off > 0; off >>= 1) s += __shfl_down(s, off, 64);
    if (lane == 0) enorm[wave] = s;
}

// ---------------------------------------------------------------------------
// Kernel 2: argmin.
// R4: array locals (acc[64]) -> scratch (VGPR=52, 233MB spills). Fix: 16
// NAMED scalar accumulators (SROA promotes named scalars).
// R5 bug: staging loop covered only 1024 of 4096 float2 (rows 0-15) ->
// rows 16-63 read uninitialized LDS. Fixed: q<16.
// z tile in LDS TRANSPOSED (zs2[d2][row], stride 65): hot-loop z re-reads are
// ds_read_b64. emb/enorm wave-uniform -> s_load broadcast (verified R2-R4).
// score_k = ||e_k||^2 - 2 z.e_k  (||z||^2 per-row constant, dropped)
// ---------------------------------------------------------------------------
#define EFMA(KK) { \
    const float4* e4 = emb4 + (((size_t)(kb + KK)) << 5) + (dc << 2); \
    float4 e0 = e4[0], e1 = e4[1], e2 = e4[2], e3 = e4[3]; \
    acc##KK = fmaf(zc0.x, e0.x, acc##KK); acc##KK = fmaf(zc0.y, e0.y, acc##KK); \
    acc##KK = fmaf(zc1.x, e0.z, acc##KK); acc##KK = fmaf(zc1.y, e0.w, acc##KK); \
    acc##KK = fmaf(zc2.x, e1.x, acc##KK); acc##KK = fmaf(zc2.y, e1.y, acc##KK); \
    acc##KK = fmaf(zc3.x, e1.z, acc##KK); acc##KK = fmaf(zc3.y, e1.w, acc##KK); \
    acc##KK = fmaf(zc4.x, e2.x, acc##KK); acc##KK = fmaf(zc4.y, e2.y, acc##KK); \
    acc##KK = fmaf(zc5.x, e2.z, acc##KK); acc##KK = fmaf(zc5.y, e2.w, acc##KK); \
    acc##KK = fmaf(zc6.x, e3.x, acc##KK); acc##KK = fmaf(zc6.y, e3.y, acc##KK); \
    acc##KK = fmaf(zc7.x, e3.z, acc##KK); acc##KK = fmaf(zc7.y, e3.w, acc##KK); }

#define SEL(KK) { \
    float s = fmaf(-2.0f, acc##KK, enorm[kb + KK]); \
    if (s < best) { best = s; bidx = kb + KK; } }  /* strict < => first idx */

__global__ void __launch_bounds__(256, 4)
argmin_kernel(const float* __restrict__ z,
              const float* __restrict__ emb,
              const float* __restrict__ enorm,
              int* __restrict__ idx_out) {
    // z transposed: zs2[d2][row], d2 = float2-pair index 0..63, stride 65
    __shared__ float2 zs2[64 * 65];
    __shared__ float red_min[NSLICE * 64];
    __shared__ int red_idx[NSLICE * 64];

    const int bid = blockIdx.x;            // 0..1023 row-group
    const int rowbase = bid * 64;
    const int t = threadIdx.x;
    const int lane = t & 63;
    const int wid = __builtin_amdgcn_readfirstlane(t >> 6);  // uniform slice id

    // Stage + transpose z tile: 64 rows x 64 float2 = 4096 float2, 16 rounds
    // of 256 coalesced 8B reads. (R5 bug: only 4 rounds -> rows 16-63 garbage.)
    const float2* zg2 = (const float2*)(z + (size_t)rowbase * ND);
#pragma unroll
    for (int q = 0; q < 16; q++) {
        int g = t + 256 * q;               // 0..4095
        int r = g >> 6;                    // row 0..63
        int d2 = g & 63;                   // float2 index 0..63
        zs2[d2 * 65 + r] = zg2[g];
    }
    __syncthreads();

    const float4* emb4 = (const float4*)emb;
    float best = 3.4e38f;
    int bidx = 0;
    const int k0 = wid * SLICE_K;

    for (int kt = 0; kt < SLICE_K / KTILE; kt++) {   // 64 tiles x 16 codes
        const int kb = k0 + kt * KTILE;
        float acc0 = 0.f, acc1 = 0.f, acc2 = 0.f, acc3 = 0.f;
        float acc4 = 0.f, acc5 = 0.f, acc6 = 0.f, acc7 = 0.f;
        float acc8 = 0.f, acc9 = 0.f, acc10 = 0.f, acc11 = 0.f;
        float acc12 = 0.f, acc13 = 0.f, acc14 = 0.f, acc15 = 0.f;

        for (int dc = 0; dc < 8; dc++) {             // 8 chunks of 16 floats
            const float2* zb = &zs2[(dc * 8) * 65 + lane];
            float2 zc0 = zb[0 * 65], zc1 = zb[1 * 65], zc2 = zb[2 * 65],
                   zc3 = zb[3 * 65], zc4 = zb[4 * 65], zc5 = zb[5 * 65],
                   zc6 = zb[6 * 65], zc7 = zb[7 * 65];
            EFMA(0)  EFMA(1)  EFMA(2)  EFMA(3)
            EFMA(4)  EFMA(5)  EFMA(6)  EFMA(7)
            EFMA(8)  EFMA(9)  EFMA(10) EFMA(11)
            EFMA(12) EFMA(13) EFMA(14) EFMA(15)
        }

        SEL(0)  SEL(1)  SEL(2)  SEL(3)
        SEL(4)  SEL(5)  SEL(6)  SEL(7)
        SEL(8)  SEL(9)  SEL(10) SEL(11)
        SEL(12) SEL(13) SEL(14) SEL(15)
    }

    red_min[wid * 64 + lane] = best;
    red_idx[wid * 64 + lane] = bidx;
    __syncthreads();

    if (wid == 0) {
        float bm = red_min[lane];
        int bi = red_idx[lane];
#pragma unroll
        for (int sl = 1; sl < NSLICE; sl++) {
            float m = red_min[sl * 64 + lane];
            int i2 = red_idx[sl * 64 + lane];
            if (m < bm) { bm = m; bi = i2; }  // ascending slices => first-idx ties
        }
        idx_out[rowbase + lane] = bi;
    }
}

// ---------------------------------------------------------------------------
// Kernel 3: gather + loss partial + transposed write.
// One block per (b,h): 64 w-positions x 128 d.
// ---------------------------------------------------------------------------
__global__ void out_kernel(const float* __restrict__ z,
                           const float* __restrict__ emb,
                           const int* __restrict__ idx,
                           float* __restrict__ out,
                           float* __restrict__ losspart) {
    __shared__ float zq[64 * 129];
    __shared__ int ids[64];
    __shared__ float redl[4];

    const int bid = blockIdx.x;         // b*64 + h
    const int b = bid >> 6;
    const int h = bid & 63;
    const int rowbase = bid * 64;
    const int t = threadIdx.x;

    if (t < 64) ids[t] = idx[rowbase + t];
    __syncthreads();

    const int d = t & 127;
    const int w0 = t >> 7;
    float lsum = 0.f;
#pragma unroll
    for (int wq = 0; wq < 32; wq++) {
        int w = w0 + 2 * wq;
        float e = emb[(size_t)ids[w] * ND + d];
        float zv = z[((size_t)(rowbase + w)) * ND + d];
        float df = e - zv;
        lsum = fmaf(df, df, lsum);
        zq[w * 129 + d] = e;
    }
#pragma unroll
    for (int off = 32; off > 0; off >>= 1) lsum += __shfl_down(lsum, off, 64);
    if ((t & 63) == 0) redl[t >> 6] = lsum;
    __syncthreads();    // also fences zq writes for pass B
    if (t == 0) losspart[bid] = redl[0] + redl[1] + redl[2] + redl[3];

    const int w = t & 63;
    const int dq = t >> 6;
#pragma unroll
    for (int dd0 = 0; dd0 < 32; dd0++) {
        int dd = dq + 4 * dd0;
        out[(((size_t)b * ND + dd) * NH + h) * NW + w] = zq[w * 129 + dd];
    }
}

// ---------------------------------------------------------------------------
// Kernel 4: final loss reduce
// ---------------------------------------------------------------------------
__global__ void loss_kernel(const float* __restrict__ losspart,
                            float* __restrict__ out) {
    __shared__ float redl[4];
    const int t = threadIdx.x;
    float s = 0.f;
#pragma unroll
    for (int i = 0; i < 4; i++) s += losspart[t + 256 * i];
#pragma unroll
    for (int off = 32; off > 0; off >>= 1) s += __shfl_down(s, off, 64);
    if ((t & 63) == 0) redl[t >> 6] = s;
    __syncthreads();
    if (t == 0) {
        float total = redl[0] + redl[1] + redl[2] + redl[3];
        out[OUT_ELEMS] = 1.25f * total / (float)OUT_ELEMS;
    }
}

// ---------------------------------------------------------------------------
extern "C" void kernel_launch(void* const* d_in, const int* in_sizes, int n_in,
                              void* d_out, int out_size, void* d_ws, size_t ws_size,
                              hipStream_t stream) {
    const float* z = (const float*)d_in[0];      // [16,64,64,128] fp32
    const float* emb = (const float*)d_in[1];    // [4096,128] fp32
    float* out = (float*)d_out;                  // 8388608 + 1 fp32

    char* ws = (char*)d_ws;
    int* ws_idx = (int*)ws;                          // NROWS ints   (256 KB)
    float* ws_enorm = (float*)(ws + 262144);         // NK floats    (16 KB)
    float* ws_losspart = (float*)(ws + 262144 + 16384);  // 1024 floats

    enorm_kernel<<<NK / 4, 256, 0, stream>>>(emb, ws_enorm);
    argmin_kernel<<<NROWS / 64, 256, 0, stream>>>(z, emb, ws_enorm, ws_idx);
    out_kernel<<<NB * NH, 256, 0, stream>>>(z, emb, ws_idx, out, ws_losspart);
    loss_kernel<<<1, 256, 0, stream>>>(ws_losspart, out);
}